// Round 12
// baseline (209.219 us; speedup 1.0000x reference)
//
#include <hip/hip_runtime.h>
#include <hip/hip_bf16.h>
#include <stdint.h>

#define MROWS 16384   // B*S
#define KDIM  2048
#define NDIM  2048
#define LEAFD 13
#define RANKD 4

typedef __bf16 bf16x8 __attribute__((ext_vector_type(8)));
typedef float  f32x4  __attribute__((ext_vector_type(4)));

// ---------------------------------------------------------------------------
// Kernel 1: w_bf[o,i] = bf16( weight[o,i] + sum_r L0[r,o2,i2]*L1[r,o1,i1]*L2[r,o0,i0] )
// ---------------------------------------------------------------------------
__global__ void build_w_kernel(const float* __restrict__ weight,
                               const float* __restrict__ leaf,
                               __hip_bfloat16* __restrict__ wbf) {
    __shared__ float ll[3 * RANKD * LEAFD * LEAFD];
    for (int t = threadIdx.x; t < 3 * RANKD * LEAFD * LEAFD; t += blockDim.x)
        ll[t] = leaf[t];
    __syncthreads();
    int idx = blockIdx.x * blockDim.x + threadIdx.x;
    if (idx >= NDIM * KDIM) return;
    int o = idx / KDIM, i = idx % KDIM;
    int o2 = o / 169, o1 = (o / 13) % 13, o0 = o % 13;
    int i2 = i / 169, i1 = (i / 13) % 13, i0 = i % 13;
    float d = 0.f;
#pragma unroll
    for (int r = 0; r < RANKD; ++r) {
        float a = ll[( r            * LEAFD + o2) * LEAFD + i2];
        float b = ll[((RANKD   + r) * LEAFD + o1) * LEAFD + i1];
        float c = ll[((2*RANKD + r) * LEAFD + o0) * LEAFD + i0];
        d += a * b * c;
    }
    wbf[idx] = __float2bfloat16(weight[idx] + d);
}

// ---------------------------------------------------------------------------
// Kernel 2: fp32 -> bf16 conversion of activations (8 floats/thread)
// ---------------------------------------------------------------------------
__global__ void cvt_kernel(const float* __restrict__ x,
                           __hip_bfloat16* __restrict__ xb, int n) {
    long stride = (long)gridDim.x * blockDim.x * 8;
    for (long idx = ((long)blockIdx.x * blockDim.x + threadIdx.x) * 8; idx < n; idx += stride) {
        float4 v0 = *reinterpret_cast<const float4*>(x + idx);
        float4 v1 = *reinterpret_cast<const float4*>(x + idx + 4);
        __hip_bfloat16 tmp[8];
        tmp[0] = __float2bfloat16(v0.x); tmp[1] = __float2bfloat16(v0.y);
        tmp[2] = __float2bfloat16(v0.z); tmp[3] = __float2bfloat16(v0.w);
        tmp[4] = __float2bfloat16(v1.x); tmp[5] = __float2bfloat16(v1.y);
        tmp[6] = __float2bfloat16(v1.z); tmp[7] = __float2bfloat16(v1.w);
        *reinterpret_cast<uint4*>(xb + idx) = *reinterpret_cast<const uint4*>(tmp);
    }
}

// ---------------------------------------------------------------------------
// Kernel 3: m201-faithful 8-phase GEMM. 256x256 tile, BK=64, 16x16x32 MFMA,
// 8 waves (2M x 4N), per-wave 128x64. Iteration = 2 K-tiles = 8 phases;
// phase = one C-quadrant (qm,qn) x K=64 = 16 MFMA.
//   p1: RD_A(band0) 8 + RD_B(qn0) 4   p2: RD_B(qn1) 4
//   p3: RD_A(band1) 8                 p4: 0 reads (all frags held)
// A-frags held 2 phases, B-frags held 4. One half-tile (16KB, 2 gloads)
// staged per phase; vmcnt(4) fences at phases 4 and 8 only.
// LDS per buf (64KB): [A.h0][A.h1][B.h0][B.h1] x 16KB; 2 bufs = 128KB.
// Slot liveness: B-halves free after p2, A-halves after p3 ->
//   p3,p4: B(T+2)->buf0   p5,p6: A(T+2)->buf0
//   p7,p8: B(T+3)->buf1   p1',p2': A(T+3)->buf1
// Swizzle: involution on 16B chunks within each 16KB half-tile,
// swz(p)=p^((p>>3)&7) (R2: measured 0 conflicts; quarter-wave = 2-way free).
// ks -> ^64; qm -> +8192; qn -> +4096 (row&7 invariant under +32/+64 rows).
// ---------------------------------------------------------------------------

__device__ __forceinline__ void gload16(const __hip_bfloat16* g, char* l) {
    __builtin_amdgcn_global_load_lds((const __attribute__((address_space(1))) void*)g,
                                     (__attribute__((address_space(3))) void*)l,
                                     16, 0, 0);
}

#define STAGE_A(kt, h, BUF) do {                                                        \
    gload16(Abase + (size_t)((h)*128)*KDIM + (kt)*64 + gOff0,                           \
            smemc + (BUF)*65536 + (h)*16384 + sOff0);                                   \
    gload16(Abase + (size_t)((h)*128)*KDIM + (kt)*64 + gOff1,                           \
            smemc + (BUF)*65536 + (h)*16384 + sOff1);                                   \
} while (0)
#define STAGE_B(kt, h, BUF) do {                                                        \
    gload16(Bbase + (size_t)((h)*128)*KDIM + (kt)*64 + gOff0,                           \
            smemc + (BUF)*65536 + 32768 + (h)*16384 + sOff0);                           \
    gload16(Bbase + (size_t)((h)*128)*KDIM + (kt)*64 + gOff1,                           \
            smemc + (BUF)*65536 + 32768 + (h)*16384 + sOff1);                           \
} while (0)

#define RD(off) (*(const bf16x8*)(smemc + (off)))

#define RD_A(BUF, qm) do {                                                              \
    a00 = RD((BUF)*65536 + (qm)*8192 + offA0);                                          \
    a01 = RD((BUF)*65536 + (qm)*8192 + (offA0 ^ 64));                                   \
    a10 = RD((BUF)*65536 + (qm)*8192 + offA1);                                          \
    a11 = RD((BUF)*65536 + (qm)*8192 + (offA1 ^ 64));                                   \
    a20 = RD((BUF)*65536 + (qm)*8192 + offA2);                                          \
    a21 = RD((BUF)*65536 + (qm)*8192 + (offA2 ^ 64));                                   \
    a30 = RD((BUF)*65536 + (qm)*8192 + offA3);                                          \
    a31 = RD((BUF)*65536 + (qm)*8192 + (offA3 ^ 64));                                   \
} while (0)

#define RD_B0(BUF) do {                                                                 \
    b000 = RD((BUF)*65536 + offB0);       b001 = RD((BUF)*65536 + (offB0 ^ 64));        \
    b010 = RD((BUF)*65536 + offB1);       b011 = RD((BUF)*65536 + (offB1 ^ 64));        \
} while (0)
#define RD_B1(BUF) do {                                                                 \
    b100 = RD((BUF)*65536 + 4096 + offB0); b101 = RD((BUF)*65536 + 4096 + (offB0 ^ 64)); \
    b110 = RD((BUF)*65536 + 4096 + offB1); b111 = RD((BUF)*65536 + 4096 + (offB1 ^ 64)); \
} while (0)

// One quadrant x K=64: 16 MFMA. N0=qn*2, N1=qn*2+1.
#define MFMA_QD(qm, B00,B01,B10,B11, N0, N1) do {                                               \
    acc[(qm)*4+0][N0] = __builtin_amdgcn_mfma_f32_16x16x32_bf16(a00, B00, acc[(qm)*4+0][N0],0,0,0); \
    acc[(qm)*4+1][N0] = __builtin_amdgcn_mfma_f32_16x16x32_bf16(a10, B00, acc[(qm)*4+1][N0],0,0,0); \
    acc[(qm)*4+2][N0] = __builtin_amdgcn_mfma_f32_16x16x32_bf16(a20, B00, acc[(qm)*4+2][N0],0,0,0); \
    acc[(qm)*4+3][N0] = __builtin_amdgcn_mfma_f32_16x16x32_bf16(a30, B00, acc[(qm)*4+3][N0],0,0,0); \
    acc[(qm)*4+0][N1] = __builtin_amdgcn_mfma_f32_16x16x32_bf16(a00, B10, acc[(qm)*4+0][N1],0,0,0); \
    acc[(qm)*4+1][N1] = __builtin_amdgcn_mfma_f32_16x16x32_bf16(a10, B10, acc[(qm)*4+1][N1],0,0,0); \
    acc[(qm)*4+2][N1] = __builtin_amdgcn_mfma_f32_16x16x32_bf16(a20, B10, acc[(qm)*4+2][N1],0,0,0); \
    acc[(qm)*4+3][N1] = __builtin_amdgcn_mfma_f32_16x16x32_bf16(a30, B10, acc[(qm)*4+3][N1],0,0,0); \
    acc[(qm)*4+0][N0] = __builtin_amdgcn_mfma_f32_16x16x32_bf16(a01, B01, acc[(qm)*4+0][N0],0,0,0); \
    acc[(qm)*4+1][N0] = __builtin_amdgcn_mfma_f32_16x16x32_bf16(a11, B01, acc[(qm)*4+1][N0],0,0,0); \
    acc[(qm)*4+2][N0] = __builtin_amdgcn_mfma_f32_16x16x32_bf16(a21, B01, acc[(qm)*4+2][N0],0,0,0); \
    acc[(qm)*4+3][N0] = __builtin_amdgcn_mfma_f32_16x16x32_bf16(a31, B01, acc[(qm)*4+3][N0],0,0,0); \
    acc[(qm)*4+0][N1] = __builtin_amdgcn_mfma_f32_16x16x32_bf16(a01, B11, acc[(qm)*4+0][N1],0,0,0); \
    acc[(qm)*4+1][N1] = __builtin_amdgcn_mfma_f32_16x16x32_bf16(a11, B11, acc[(qm)*4+1][N1],0,0,0); \
    acc[(qm)*4+2][N1] = __builtin_amdgcn_mfma_f32_16x16x32_bf16(a21, B11, acc[(qm)*4+2][N1],0,0,0); \
    acc[(qm)*4+3][N1] = __builtin_amdgcn_mfma_f32_16x16x32_bf16(a31, B11, acc[(qm)*4+3][N1],0,0,0); \
} while (0)

#define BARRIER_IN do {                                     \
    __builtin_amdgcn_sched_barrier(0);                      \
    __builtin_amdgcn_s_barrier();                           \
    asm volatile("s_waitcnt lgkmcnt(0)" ::: "memory");      \
    __builtin_amdgcn_sched_barrier(0);                      \
    __builtin_amdgcn_s_setprio(1);                          \
} while (0)

#define BARRIER_OUT do {                                    \
    __builtin_amdgcn_s_setprio(0);                          \
    __builtin_amdgcn_sched_barrier(0);                      \
    __builtin_amdgcn_s_barrier();                           \
    __builtin_amdgcn_sched_barrier(0);                      \
} while (0)

#define WAIT8 asm volatile("s_waitcnt vmcnt(8)" ::: "memory")
#define WAIT4 asm volatile("s_waitcnt vmcnt(4)" ::: "memory")
#define WAIT0 asm volatile("s_waitcnt vmcnt(0)" ::: "memory")
#define WNONE do {} while (0)

// One iteration: tiles T (buf0, p1-4) and T+1 (buf1, p5-8).
#define KITER(T, S12, SMID, S78, F4_, F8_) do {                     \
    /* p1: quad(0,0) of T */                                        \
    RD_A(0, 0); RD_B0(0);                                           \
    if (S12) STAGE_A((T)+1, 0, 1);                                  \
    BARRIER_IN; MFMA_QD(0, b000,b001,b010,b011, 0,1); BARRIER_OUT;  \
    /* p2: quad(0,1) */                                             \
    RD_B1(0);                                                       \
    if (S12) STAGE_A((T)+1, 1, 1);                                  \
    BARRIER_IN; MFMA_QD(0, b100,b101,b110,b111, 2,3); BARRIER_OUT;  \
    /* p3: quad(1,0) */                                             \
    RD_A(0, 1);                                                     \
    if (SMID) STAGE_B((T)+2, 0, 0);                                 \
    BARRIER_IN; MFMA_QD(1, b000,b001,b010,b011, 0,1); BARRIER_OUT;  \
    /* p4: quad(1,1) — zero reads */                                \
    if (SMID) STAGE_B((T)+2, 1, 0);                                 \
    F4_;                                                            \
    BARRIER_IN; MFMA_QD(1, b100,b101,b110,b111, 2,3); BARRIER_OUT;  \
    /* p5: quad(0,0) of T+1 */                                      \
    RD_A(1, 0); RD_B0(1);                                           \
    if (SMID) STAGE_A((T)+2, 0, 0);                                 \
    BARRIER_IN; MFMA_QD(0, b000,b001,b010,b011, 0,1); BARRIER_OUT;  \
    /* p6: quad(0,1) */                                             \
    RD_B1(1);                                                       \
    if (SMID) STAGE_A((T)+2, 1, 0);                                 \
    BARRIER_IN; MFMA_QD(0, b100,b101,b110,b111, 2,3); BARRIER_OUT;  \
    /* p7: quad(1,0) */                                             \
    RD_A(1, 1);                                                     \
    if (S78) STAGE_B((T)+3, 0, 1);                                  \
    BARRIER_IN; MFMA_QD(1, b000,b001,b010,b011, 0,1); BARRIER_OUT;  \
    /* p8: quad(1,1) — zero reads */                                \
    if (S78) STAGE_B((T)+3, 1, 1);                                  \
    F8_;                                                            \
    BARRIER_IN; MFMA_QD(1, b100,b101,b110,b111, 2,3); BARRIER_OUT;  \
} while (0)

__global__ __launch_bounds__(512, 1) void gemm8p_kernel(const __hip_bfloat16* __restrict__ A,
                                                        const __hip_bfloat16* __restrict__ Wb,
                                                        const float* __restrict__ bias,
                                                        float* __restrict__ C) {
    __shared__ __align__(16) char smem_raw[2 * 65536];   // 128 KiB
    char* smemc = smem_raw;

    const int tid  = threadIdx.x;
    const int lane = tid & 63;
    const int wid  = tid >> 6;        // 0..7
    const int wr   = wid >> 2;        // 0..1  (M half)
    const int wc   = wid & 3;         // 0..3  (N quarter)

    // T1: XCD-aware swizzle (nwg=512, 512%8==0 -> bijective).
    const int bid = blockIdx.x;
    const int swz = (bid & 7) * 64 + (bid >> 3);
    const int bn  = swz >> 6;         // 0..7
    const int bm  = swz & 63;         // 0..63

    const __hip_bfloat16* Abase = A  + (size_t)bm * 256 * KDIM;
    const __hip_bfloat16* Bbase = Wb + (size_t)bn * 256 * KDIM;

    // --- staging source (inverse involution on 16B chunks of a 16KB half) ---
    // dest chunk c = wid*128 + j*64 + lane; src chunk s = c ^ ((c>>3)&7);
    // row = s>>3 (0..127), col = s&7 -> src elem off = row*KDIM + col*8.
    int gOff0, gOff1;
    {
        const int c0 = wid * 128 + lane;
        const int c1 = c0 + 64;
        const int s0 = c0 ^ ((c0 >> 3) & 7);
        const int s1 = c1 ^ ((c1 >> 3) & 7);
        gOff0 = (s0 >> 3) * KDIM + (s0 & 7) * 8;
        gOff1 = (s1 >> 3) * KDIM + (s1 & 7) * 8;
    }
    const int sOff0 = wid * 2048;          // bytes (wave-uniform)
    const int sOff1 = wid * 2048 + 1024;

    // --- fragment read base offsets (qm=0, qn=0, ks=0); derived others:
    //     ks=1 -> ^64 ; qm=1 -> +8192 ; qn=1 -> +4096 ---
    const int rsel = lane & 15;
    const int kq   = lane >> 4;            // 0..3
    int offA0, offA1, offA2, offA3, offB0, offB1;
    {
        const int abase = wr * 16384;
#pragma unroll
        for (int mf = 0; mf < 4; ++mf) {
            const int row = mf * 16 + rsel;                 // 0..63
            const int off = abase + row * 128 + (kq ^ (row & 7)) * 16;
            if (mf == 0) offA0 = off; else if (mf == 1) offA1 = off;
            else if (mf == 2) offA2 = off; else offA3 = off;
        }
        const int bbase = 32768 + (wc >> 1) * 16384;
#pragma unroll
        for (int nf = 0; nf < 2; ++nf) {
            const int row = (wc & 1) * 64 + nf * 16 + rsel; // 0..127
            const int off = bbase + row * 128 + (kq ^ (row & 7)) * 16;
            if (nf == 0) offB0 = off; else offB1 = off;
        }
    }

    f32x4 acc[8][4];
#pragma unroll
    for (int m = 0; m < 8; ++m)
#pragma unroll
        for (int n = 0; n < 4; ++n)
            acc[m][n] = (f32x4){0.f, 0.f, 0.f, 0.f};

    bf16x8 a00, a01, a10, a11, a20, a21, a30, a31;
    bf16x8 b000, b001, b010, b011, b100, b101, b110, b111;

    // --- prologue: stage t0 -> buf0, t1 -> buf1 (16 loads/wave) ---
    STAGE_A(0, 0, 0); STAGE_A(0, 1, 0); STAGE_B(0, 0, 0); STAGE_B(0, 1, 0);
    STAGE_A(1, 0, 1); STAGE_A(1, 1, 1); STAGE_B(1, 0, 1); STAGE_B(1, 1, 1);
    WAIT8;                    // t0 landed; t1's 8 loads may stay in flight
    __builtin_amdgcn_sched_barrier(0);
    __builtin_amdgcn_s_barrier();
    __builtin_amdgcn_sched_barrier(0);

    // --- main loop: 32 K-tiles = 16 iterations ---
    KITER(0, 0, 1, 1, WAIT4, WAIT4);          // i=0 (t1.A came from prologue)
    for (int i = 1; i < 15; ++i) {
        KITER(2 * i, 1, 1, 1, WAIT4, WAIT4);
    }
    KITER(30, 1, 0, 0, WAIT0, WNONE);         // i=15: stages t31.A at p1,p2

    // --- epilogue: C/D layout col = lane&15, row = (lane>>4)*4 + r ---
    const int col0 = rsel;
    const int r0   = kq * 4;
#pragma unroll
    for (int n = 0; n < 4; ++n) {
        const int cg = bn * 256 + wc * 64 + n * 16 + col0;
        const float bv = bias[cg];
#pragma unroll
        for (int m = 0; m < 8; ++m) {
            const size_t rg = (size_t)bm * 256 + wr * 128 + m * 16 + r0;
#pragma unroll
            for (int r = 0; r < 4; ++r)
                C[(rg + r) * NDIM + cg] = acc[m][n][r] + bv;
        }
    }
}

// ---------------------------------------------------------------------------
// Fallback: naive fused fp32 GEMM (only if workspace too small).
// ---------------------------------------------------------------------------
__global__ void naive_kernel(const float* __restrict__ x,
                             const float* __restrict__ leaf,
                             const float* __restrict__ W,
                             const float* __restrict__ bias,
                             float* __restrict__ out) {
    long idx = (long)blockIdx.x * blockDim.x + threadIdx.x;
    if (idx >= (long)MROWS * NDIM) return;
    int  o = (int)(idx % NDIM);
    long m = idx / NDIM;
    int o2 = o / 169, o1 = (o / 13) % 13, o0 = o % 13;
    float acc = 0.f;
    for (int i = 0; i < KDIM; ++i) {
        int i2 = i / 169, i1 = (i / 13) % 13, i0 = i % 13;
        float d = 0.f;
#pragma unroll
        for (int r = 0; r < RANKD; ++r)
            d += leaf[( r     * LEAFD + o2) * LEAFD + i2]
               * leaf[((4 + r) * LEAFD + o1) * LEAFD + i1]
               * leaf[((8 + r) * LEAFD + o0) * LEAFD + i0];
        acc += x[m * KDIM + i] * (W[(long)o * KDIM + i] + d);
    }
    out[idx] = acc + bias[o];
}

// ---------------------------------------------------------------------------
extern "C" void kernel_launch(void* const* d_in, const int* in_sizes, int n_in,
                              void* d_out, int out_size, void* d_ws, size_t ws_size,
                              hipStream_t stream) {
    const float* x      = (const float*)d_in[0];
    const float* leaf   = (const float*)d_in[1];
    const float* weight = (const float*)d_in[2];
    const float* bias   = (const float*)d_in[3];
    float* out = (float*)d_out;

    const size_t needA = (size_t)MROWS * KDIM * sizeof(__hip_bfloat16);  // 64 MiB
    const size_t needW = (size_t)NDIM  * KDIM * sizeof(__hip_bfloat16);  // 8 MiB

    if (ws_size >= needA + needW) {
        __hip_bfloat16* xb = (__hip_bfloat16*)d_ws;
        __hip_bfloat16* wb = (__hip_bfloat16*)((char*)d_ws + needA);
        build_w_kernel<<<(NDIM * KDIM + 255) / 256, 256, 0, stream>>>(weight, leaf, wb);
        cvt_kernel<<<2048, 256, 0, stream>>>(x, xb, MROWS * KDIM);
        gemm8p_kernel<<<(MROWS / 256) * (NDIM / 256), 512, 0, stream>>>(xb, wb, bias, out);
    } else {
        long total = (long)MROWS * NDIM;
        naive_kernel<<<(int)((total + 255) / 256), 256, 0, stream>>>(x, leaf, weight, bias, out);
    }
}